// Round 11
// baseline (123.781 us; speedup 1.0000x reference)
//
#include <hip/hip_runtime.h>

typedef _Float16 f16x8  __attribute__((ext_vector_type(8)));
typedef _Float16 f16x4  __attribute__((ext_vector_type(4)));
typedef _Float16 f16x2  __attribute__((ext_vector_type(2)));
typedef float    f32x4  __attribute__((ext_vector_type(4)));
typedef float    f32x16 __attribute__((ext_vector_type(16)));

#define MFMA32(a, b, c) __builtin_amdgcn_mfma_f32_32x32x16_f16((a), (b), (c), 0, 0, 0)

static constexpr int SEQ   = 2048;
static constexpr int DIM   = 128;
static constexpr int QBLK  = 128;          // 4 waves x 32 q-rows
static constexpr int KVBLK = 32;           // kv rows per tile
static constexpr int NKT   = SEQ / KVBLK;  // 64
static constexpr int BH    = 2 * 16;
static constexpr int KSTR  = 136;          // K LDS row stride (f16), 272B padded
static constexpr int VSTR  = 40;           // Vt LDS row stride (f16), 80B padded

// o = exp(QK^T - rowmax) @ V  (unnormalized, fp32 in/out)
// r10 core + QK-one-tile-ahead pipeline (T15): iter t computes QK(t+1) into
// stNext while softmax+PV consume stCur from the previous iteration -> the
// QK->softmax dependency spans a whole iteration; softmax VALU fills MFMA
// stall slots. Double-buffered LDS, 2 barriers/iter.
__global__ __launch_bounds__(256, 2)
void fa_fwd_kernel(const float* __restrict__ Qg, const float* __restrict__ Kg,
                   const float* __restrict__ Vg, float* __restrict__ Og)
{
    __shared__ __align__(16) _Float16 Ksh[2][KVBLK * KSTR];
    __shared__ __align__(16) _Float16 Vt[2][DIM * VSTR];

    const int tid  = threadIdx.x;
    const int wv   = tid >> 6;
    const int lane = tid & 63;
    const int lq   = lane & 31;   // q column (and K A-row) owned by this lane
    const int lh   = lane >> 5;   // half: 0/1

    // XCD swizzle: all 16 q-tiles of one bh -> one XCD (K/V L2-resident)
    const int bi = blockIdx.x;
    const int bh = (bi & 7) + 8 * (bi >> 7);
    const int qt = (bi >> 3) & 15;

    const size_t base = (size_t)bh * SEQ * DIM;
    const float* Qp = Qg + base;
    const float* Kp = Kg + base;
    const float* Vp = Vg + base;
    float*       Op = Og + base;

    const int q0 = qt * QBLK + wv * 32;

    // ---- Q fragment (B-operand: col q = lq, elems d = 16t + 8*lh + j), x log2(e)
    constexpr float LOG2E = 1.44269504088896340736f;
    f16x8 qh[8];
    {
        const float* qs = Qp + (size_t)(q0 + lq) * DIM + 8 * lh;
#pragma unroll
        for (int t = 0; t < 8; ++t) {
            const float4 a = *(const float4*)(qs + 16 * t);
            const float4 b = *(const float4*)(qs + 16 * t + 4);
            float xs[8] = {a.x, a.y, a.z, a.w, b.x, b.y, b.z, b.w};
            f16x8 h;
#pragma unroll
            for (int e = 0; e < 8; ++e) h[e] = (_Float16)(xs[e] * LOG2E);
            qh[t] = h;
        }
    }

    // O^T accumulators: acc[dm][r] = O^T[d = 32*dm + (r&3)+8*(r>>2)+4*lh][q = lq]
    f32x16 acc[4];
#pragma unroll
    for (int a = 0; a < 4; ++a)
#pragma unroll
        for (int r = 0; r < 16; ++r) acc[a][r] = 0.0f;

    float mrow  = -3.0e38f;   // running (deferred) max, log2 units
    float mtrue = -3.0e38f;   // true running max, log2 units

    // staging maps (all static register indexing)
    const int ksr = tid >> 3, kc0 = (tid & 7) * 16;   // K: 8 threads/row, 16 floats
    const int vc  = tid & 31;                         // V: d cols {vc,+32,+64,+96}
    const int vk  = (tid >> 5) * 4;                   //    x 4 consecutive k rows
    const float* kb = Kp + (size_t)ksr * DIM + kc0;
    const float* vb = Vp + (size_t)vk * DIM + vc;

    float4 kreg[4];
    float  vreg[4][4];   // [d-col j][k-row r]

    auto stage = [&](int b) {
#pragma unroll
        for (int g = 0; g < 2; ++g) {
            float xs[8] = {kreg[2*g].x, kreg[2*g].y, kreg[2*g].z, kreg[2*g].w,
                           kreg[2*g+1].x, kreg[2*g+1].y, kreg[2*g+1].z, kreg[2*g+1].w};
            f16x8 h;
#pragma unroll
            for (int e = 0; e < 8; ++e) h[e] = (_Float16)xs[e];
            *(f16x8*)((char*)&Ksh[b][0] + (ksr * KSTR + kc0 + 8 * g) * 2) = h;
        }
#pragma unroll
        for (int j = 0; j < 4; ++j) {
            const int d = vc + 32 * j;
            f16x4 tv = {(_Float16)vreg[j][0], (_Float16)vreg[j][1],
                        (_Float16)vreg[j][2], (_Float16)vreg[j][3]};
            *(f16x4*)((char*)&Vt[b][0] + (d * VSTR + vk) * 2) = tv;
        }
    };
    auto loadT = [&](int t) {
        const float* ks_ = kb + (size_t)t * KVBLK * DIM;
        const float* vs_ = vb + (size_t)t * KVBLK * DIM;
#pragma unroll
        for (int u = 0; u < 4; ++u) kreg[u] = *(const float4*)(ks_ + u * 4);
#pragma unroll
        for (int j = 0; j < 4; ++j)
#pragma unroll
            for (int r = 0; r < 4; ++r) vreg[j][r] = vs_[(size_t)r * DIM + 32 * j];
    };
    // QK^T of the tile in LDS buffer b: st[r] = S'^T[k=(r&3)+8*(r>>2)+4*lh][q=lq]
    auto qk = [&](int b) -> f32x16 {
        const char* Kc = (const char*)&Ksh[b][0];
        f32x16 s0, s1;
#pragma unroll
        for (int r = 0; r < 16; ++r) { s0[r] = 0.0f; s1[r] = 0.0f; }
        __builtin_amdgcn_s_setprio(1);
#pragma unroll
        for (int t = 0; t < 4; ++t) {
            f16x8 ka = *(const f16x8*)(Kc + (lq * KSTR + 32 * t + 8 * lh) * 2);
            f16x8 kc = *(const f16x8*)(Kc + (lq * KSTR + 32 * t + 16 + 8 * lh) * 2);
            s0 = MFMA32(ka, qh[2 * t], s0);
            s1 = MFMA32(kc, qh[2 * t + 1], s1);
        }
        __builtin_amdgcn_s_setprio(0);
        return s0 + s1;
    };

    // prologue: tile 0 staged; tile 1 in regs; scores for tile 0 in stCur
    loadT(0);
    stage(0);
    loadT(1);
    __syncthreads();
    f32x16 stCur = qk(0);

    for (int kt = 0; kt < NKT; ++kt) {
        const int cur = kt & 1;
        const bool haveN = (kt + 1 < NKT);

        __syncthreads();   // PV(kt-1) readers done with buf[cur^1]
        if (haveN)         stage(cur ^ 1);   // tile kt+1 (regs loaded last iter)
        if (kt + 2 < NKT)  loadT(kt + 2);    // issue tile kt+2 loads
        __builtin_amdgcn_sched_barrier(0);   // pin load issue here
        __syncthreads();   // stage(kt+1) visible

        // ---- QK(t+1) ahead (MFMAs independent of everything below)
        f32x16 stN;
        if (haveN) stN = qk(cur ^ 1);

        // ---- softmax on stCur (tile kt); halves l and l^32 share q-col lq
        float tmax = fmaxf(fmaxf(fmaxf(stCur[0], stCur[1]), fmaxf(stCur[2], stCur[3])),
                           fmaxf(fmaxf(stCur[4], stCur[5]), fmaxf(stCur[6], stCur[7])));
        tmax = fmaxf(tmax,
                     fmaxf(fmaxf(fmaxf(stCur[8], stCur[9]), fmaxf(stCur[10], stCur[11])),
                           fmaxf(fmaxf(stCur[12], stCur[13]), fmaxf(stCur[14], stCur[15]))));
        tmax = fmaxf(tmax, __shfl_xor(tmax, 32));
        mtrue = fmaxf(mtrue, tmax);

        // defer-max (T13): rescale only when some row grew by > THR (log2 units)
        if (!__all(tmax - mrow <= 6.0f)) {
            const float mn  = fmaxf(mrow, tmax);
            const float scl = __builtin_exp2f(mrow - mn);
            mrow = mn;
#pragma unroll
            for (int a = 0; a < 4; ++a)
#pragma unroll
                for (int r = 0; r < 16; ++r) acc[a][r] *= scl;
        }

        // ---- P^T packed f16 (bounded by 2^6 = 64)
        int pk[8];
#pragma unroll
        for (int i = 0; i < 8; ++i) {
            f16x2 e = {(_Float16)__builtin_exp2f(stCur[2 * i] - mrow),
                       (_Float16)__builtin_exp2f(stCur[2 * i + 1] - mrow)};
            pk[i] = __builtin_bit_cast(int, e);
        }

        // ---- PV: O^T += V^T P^T (k = 16s + 8lh + j); one shfl_xor each direction
        const char* Vc = (const char*)&Vt[cur][0];
#pragma unroll
        for (int s = 0; s < 2; ++s) {
            const int z1 = __shfl_xor(lh ? pk[4*s+0] : pk[4*s+2], 32);
            const int z2 = __shfl_xor(lh ? pk[4*s+1] : pk[4*s+3], 32);
            union { int i[4]; f16x8 v; } u;
            u.i[0] = lh ? z1 : pk[4*s+0];
            u.i[1] = lh ? z2 : pk[4*s+1];
            u.i[2] = lh ? pk[4*s+2] : z1;
            u.i[3] = lh ? pk[4*s+3] : z2;
            const f16x8 pb = u.v;
            __builtin_amdgcn_s_setprio(1);
#pragma unroll
            for (int dm = 0; dm < 4; ++dm) {
                const int d = dm * 32 + lq;
                f16x8 va = *(const f16x8*)(Vc + (d * VSTR + 16 * s + 8 * lh) * 2);
                acc[dm] = MFMA32(va, pb, acc[dm]);
            }
            __builtin_amdgcn_s_setprio(0);
        }

        if (haveN) stCur = stN;
    }

    // ---- final correction to the true global row max (reference is unnormalized)
    const float fin = __builtin_exp2f(mrow - mtrue);
#pragma unroll
    for (int a = 0; a < 4; ++a)
#pragma unroll
        for (int r = 0; r < 16; ++r) acc[a][r] *= fin;

    // ---- store O: reg r of acc[dm] -> col d = 32*dm + 8*(r>>2) + 4*lh + (r&3)
    float* ob = Op + (size_t)(q0 + lq) * DIM + 4 * lh;
#pragma unroll
    for (int dm = 0; dm < 4; ++dm)
#pragma unroll
        for (int kp = 0; kp < 4; ++kp) {
            f32x4 v4 = {acc[dm][4*kp], acc[dm][4*kp+1], acc[dm][4*kp+2], acc[dm][4*kp+3]};
            *(f32x4*)(ob + dm * 32 + kp * 8) = v4;
        }
}

extern "C" void kernel_launch(void* const* d_in, const int* in_sizes, int n_in,
                              void* d_out, int out_size, void* d_ws, size_t ws_size,
                              hipStream_t stream) {
    const float* q = (const float*)d_in[0];
    const float* k = (const float*)d_in[1];
    const float* v = (const float*)d_in[2];
    float* o = (float*)d_out;
    dim3 grid((SEQ / QBLK) * BH);   // 512 blocks = 2/CU, XCD-swizzled in-kernel
    fa_fwd_kernel<<<grid, dim3(256), 0, stream>>>(q, k, v, o);
}

// Round 12
// 116.309 us; speedup vs baseline: 1.0642x; 1.0642x over previous
//
#include <hip/hip_runtime.h>

typedef _Float16 f16x8  __attribute__((ext_vector_type(8)));
typedef _Float16 f16x4  __attribute__((ext_vector_type(4)));
typedef _Float16 f16x2  __attribute__((ext_vector_type(2)));
typedef float    f32x4  __attribute__((ext_vector_type(4)));
typedef float    f32x16 __attribute__((ext_vector_type(16)));
typedef int      i32x2  __attribute__((ext_vector_type(2)));

#define MFMA32(a, b, c) __builtin_amdgcn_mfma_f32_32x32x16_f16((a), (b), (c), 0, 0, 0)

static constexpr int SEQ   = 2048;
static constexpr int DIM   = 128;
static constexpr int QBLK  = 128;          // 4 waves x 32 q-rows
static constexpr int KVBLK = 32;           // kv rows per tile
static constexpr int NKT   = SEQ / KVBLK;  // 64
static constexpr int BH    = 2 * 16;
static constexpr int KSTR  = 136;          // K LDS row stride (f16), 272B padded
static constexpr int VSTR  = 40;           // Vt LDS row stride (f16), 80B padded

// o = exp(QK^T - rowmax) @ V  (unnormalized, fp32 in/out)
// r10 structure (dbuf LDS, 1 barrier/iter, pinned reg prefetch) with the PV
// cross-half P-exchange done by v_permlane32_swap (VALU) instead of
// ds_bpermute shfl + cndmask. Row-max reduce keeps shfl_xor (the r5 NaN was
// same-register permlane32_swap(tmax,tmax); P-exchange uses distinct regs).
__global__ __launch_bounds__(256, 2)
void fa_fwd_kernel(const float* __restrict__ Qg, const float* __restrict__ Kg,
                   const float* __restrict__ Vg, float* __restrict__ Og)
{
    __shared__ __align__(16) _Float16 Ksh[2][KVBLK * KSTR];
    __shared__ __align__(16) _Float16 Vt[2][DIM * VSTR];

    const int tid  = threadIdx.x;
    const int wv   = tid >> 6;
    const int lane = tid & 63;
    const int lq   = lane & 31;   // q column (and K A-row) owned by this lane
    const int lh   = lane >> 5;   // half: 0/1

    // XCD swizzle: all 16 q-tiles of one bh -> one XCD (K/V L2-resident)
    const int bi = blockIdx.x;
    const int bh = (bi & 7) + 8 * (bi >> 7);
    const int qt = (bi >> 3) & 15;

    const size_t base = (size_t)bh * SEQ * DIM;
    const float* Qp = Qg + base;
    const float* Kp = Kg + base;
    const float* Vp = Vg + base;
    float*       Op = Og + base;

    const int q0 = qt * QBLK + wv * 32;

    // ---- Q fragment (B-operand: col q = lq, elems d = 16t + 8*lh + j), x log2(e)
    constexpr float LOG2E = 1.44269504088896340736f;
    f16x8 qh[8];
    {
        const float* qs = Qp + (size_t)(q0 + lq) * DIM + 8 * lh;
#pragma unroll
        for (int t = 0; t < 8; ++t) {
            const float4 a = *(const float4*)(qs + 16 * t);
            const float4 b = *(const float4*)(qs + 16 * t + 4);
            float xs[8] = {a.x, a.y, a.z, a.w, b.x, b.y, b.z, b.w};
            f16x8 h;
#pragma unroll
            for (int e = 0; e < 8; ++e) h[e] = (_Float16)(xs[e] * LOG2E);
            qh[t] = h;
        }
    }

    // O^T accumulators: acc[dm][r] = O^T[d = 32*dm + (r&3)+8*(r>>2)+4*lh][q = lq]
    f32x16 acc[4];
#pragma unroll
    for (int a = 0; a < 4; ++a)
#pragma unroll
        for (int r = 0; r < 16; ++r) acc[a][r] = 0.0f;

    float mrow  = -3.0e38f;   // running (deferred) max, log2 units
    float mtrue = -3.0e38f;   // true running max, log2 units

    // staging maps (all static register indexing)
    const int ksr = tid >> 3, kc0 = (tid & 7) * 16;   // K: 8 threads/row, 16 floats
    const int vc  = tid & 31;                         // V: d cols {vc,+32,+64,+96}
    const int vk  = (tid >> 5) * 4;                   //    x 4 consecutive k rows
    const float* kb = Kp + (size_t)ksr * DIM + kc0;
    const float* vb = Vp + (size_t)vk * DIM + vc;

    float4 kreg[4];
    float  vreg[4][4];   // [d-col j][k-row r]

    // STAGE: convert regs to f16 and write LDS buffer `b`
    auto stage = [&](int b) {
#pragma unroll
        for (int g = 0; g < 2; ++g) {
            float xs[8] = {kreg[2*g].x, kreg[2*g].y, kreg[2*g].z, kreg[2*g].w,
                           kreg[2*g+1].x, kreg[2*g+1].y, kreg[2*g+1].z, kreg[2*g+1].w};
            f16x8 h;
#pragma unroll
            for (int e = 0; e < 8; ++e) h[e] = (_Float16)xs[e];
            *(f16x8*)((char*)&Ksh[b][0] + (ksr * KSTR + kc0 + 8 * g) * 2) = h;
        }
#pragma unroll
        for (int j = 0; j < 4; ++j) {
            const int d = vc + 32 * j;
            f16x4 tv = {(_Float16)vreg[j][0], (_Float16)vreg[j][1],
                        (_Float16)vreg[j][2], (_Float16)vreg[j][3]};
            *(f16x4*)((char*)&Vt[b][0] + (d * VSTR + vk) * 2) = tv;
        }
    };
    auto loadT = [&](int t) {
        const float* ks_ = kb + (size_t)t * KVBLK * DIM;
        const float* vs_ = vb + (size_t)t * KVBLK * DIM;
#pragma unroll
        for (int u = 0; u < 4; ++u) kreg[u] = *(const float4*)(ks_ + u * 4);
#pragma unroll
        for (int j = 0; j < 4; ++j)
#pragma unroll
            for (int r = 0; r < 4; ++r) vreg[j][r] = vs_[(size_t)r * DIM + 32 * j];
    };

    // prologue: tile 0 staged; tile 1 in regs
    loadT(0);
    stage(0);
    loadT(1);

    for (int kt = 0; kt < NKT; ++kt) {
        const int cur = kt & 1;
        __syncthreads();   // buf[cur] writes visible; buf[cur^1] readers done

        // ---- write next tile (regs loaded one full iteration ago)
        if (kt + 1 < NKT) stage(cur ^ 1);
        // ---- issue loads for tile kt+2; pin them here (don't sink into compute)
        if (kt + 2 < NKT) loadT(kt + 2);
        __builtin_amdgcn_sched_barrier(0);

        // ---- S^T = K Q^T, single pass, 2 interleaved accumulator chains
        const char* Kc = (const char*)&Ksh[cur][0];
        const char* Vc = (const char*)&Vt[cur][0];
        f32x16 s0, s1;
#pragma unroll
        for (int r = 0; r < 16; ++r) { s0[r] = 0.0f; s1[r] = 0.0f; }
        __builtin_amdgcn_s_setprio(1);
#pragma unroll
        for (int t = 0; t < 4; ++t) {
            f16x8 ka = *(const f16x8*)(Kc + (lq * KSTR + 32 * t + 8 * lh) * 2);
            f16x8 kc = *(const f16x8*)(Kc + (lq * KSTR + 32 * t + 16 + 8 * lh) * 2);
            s0 = MFMA32(ka, qh[2 * t], s0);
            s1 = MFMA32(kc, qh[2 * t + 1], s1);
        }
        __builtin_amdgcn_s_setprio(0);
        f32x16 st = s0 + s1;   // st[r] = S'^T[k = (r&3)+8*(r>>2)+4*lh][q = lq]

        // ---- online softmax (halves l and l^32 share q-col lq)
        float tmax = fmaxf(fmaxf(fmaxf(st[0], st[1]), fmaxf(st[2], st[3])),
                           fmaxf(fmaxf(st[4], st[5]), fmaxf(st[6], st[7])));
        tmax = fmaxf(tmax, fmaxf(fmaxf(fmaxf(st[8], st[9]), fmaxf(st[10], st[11])),
                                 fmaxf(fmaxf(st[12], st[13]), fmaxf(st[14], st[15]))));
        tmax = fmaxf(tmax, __shfl_xor(tmax, 32));
        mtrue = fmaxf(mtrue, tmax);

        // defer-max (T13): rescale only when some row grew by > THR (log2 units)
        if (!__all(tmax - mrow <= 6.0f)) {
            const float mn  = fmaxf(mrow, tmax);
            const float scl = __builtin_exp2f(mrow - mn);
            mrow = mn;
#pragma unroll
            for (int a = 0; a < 4; ++a)
#pragma unroll
                for (int r = 0; r < 16; ++r) acc[a][r] *= scl;
        }

        // ---- P^T packed f16 (bounded by 2^6 = 64)
        int pk[8];
#pragma unroll
        for (int i = 0; i < 8; ++i) {
            f16x2 e = {(_Float16)__builtin_exp2f(st[2 * i] - mrow),
                       (_Float16)__builtin_exp2f(st[2 * i + 1] - mrow)};
            pk[i] = __builtin_bit_cast(int, e);
        }

        // ---- PV: O^T += V^T P^T (k = 16s + 8lh + j).
        // B-frag built with v_permlane32_swap (distinct src regs; VALU-only):
        //   swap(A,B) -> A' = concat(A_lo, B_lo) = word for k-offset {0,1}+8lh_own
        //               B' = concat(A_hi, B_hi) = word for the partner half.
        // Element-verified against the r6 shfl mapping for both lh halves.
#pragma unroll
        for (int s = 0; s < 2; ++s) {
            i32x2 w02 = __builtin_amdgcn_permlane32_swap(pk[4*s+0], pk[4*s+2], false, false);
            i32x2 w13 = __builtin_amdgcn_permlane32_swap(pk[4*s+1], pk[4*s+3], false, false);
            union { int i[4]; f16x8 v; } u;
            u.i[0] = w02[0]; u.i[1] = w13[0]; u.i[2] = w02[1]; u.i[3] = w13[1];
            const f16x8 pb = u.v;
            __builtin_amdgcn_s_setprio(1);
#pragma unroll
            for (int dm = 0; dm < 4; ++dm) {
                const int d = dm * 32 + lq;
                f16x8 va = *(const f16x8*)(Vc + (d * VSTR + 16 * s + 8 * lh) * 2);
                acc[dm] = MFMA32(va, pb, acc[dm]);
            }
            __builtin_amdgcn_s_setprio(0);
        }
    }

    // ---- final correction to the true global row max (reference is unnormalized)
    const float fin = __builtin_exp2f(mrow - mtrue);
#pragma unroll
    for (int a = 0; a < 4; ++a)
#pragma unroll
        for (int r = 0; r < 16; ++r) acc[a][r] *= fin;

    // ---- store O: reg r of acc[dm] -> col d = 32*dm + 8*(r>>2) + 4*lh + (r&3)
    float* ob = Op + (size_t)(q0 + lq) * DIM + 4 * lh;
#pragma unroll
    for (int dm = 0; dm < 4; ++dm)
#pragma unroll
        for (int kp = 0; kp < 4; ++kp) {
            f32x4 v4 = {acc[dm][4*kp], acc[dm][4*kp+1], acc[dm][4*kp+2], acc[dm][4*kp+3]};
            *(f32x4*)(ob + dm * 32 + kp * 8) = v4;
        }
}

extern "C" void kernel_launch(void* const* d_in, const int* in_sizes, int n_in,
                              void* d_out, int out_size, void* d_ws, size_t ws_size,
                              hipStream_t stream) {
    const float* q = (const float*)d_in[0];
    const float* k = (const float*)d_in[1];
    const float* v = (const float*)d_in[2];
    float* o = (float*)d_out;
    dim3 grid((SEQ / QBLK) * BH);   // 512 blocks = 2/CU, XCD-swizzled in-kernel
    fa_fwd_kernel<<<grid, dim3(256), 0, stream>>>(q, k, v, o);
}